// Round 1
// baseline (30328.839 us; speedup 1.0000x reference)
//
#include <hip/hip_runtime.h>
#include <hip/hip_bf16.h>

// Bidirectional masked GRU: B=64, L=1024, IN=512, H=512, fp32 in/out.
// Persistent-kernel design: 256 blocks (1/CU, co-resident), 6 waves each.
//   block -> (dir 0..1, batch-group 0..3 [16 rows], col-block 0..31 [16 h-cols])
//   waves 0..2: gh = h @ w_hh^T strips (r,z,n); waves 3..5: gx = x @ w_ih^T strips.
//   Weight B-fragments register-resident (loaded once). h exchanged per step via
//   global bf16 buffer + per-(dir,bg,step) arrival counters (agent-scope atomics).

#define B_  64
#define L_  1024
#define IN_ 512
#define H_  512

using float4v = __attribute__((ext_vector_type(4))) float;
using short8  = __attribute__((ext_vector_type(8))) short;
using ushort4v = __attribute__((ext_vector_type(4))) unsigned short;

__device__ __forceinline__ unsigned short f2bf(float f) {
  // round-to-nearest-even bf16 (finite inputs)
  unsigned u = __float_as_uint(f);
  unsigned r = (u + 0x7fffu + ((u >> 16) & 1u)) >> 16;
  return (unsigned short)r;
}

__global__ void __launch_bounds__(512) cast_bf16_kernel(
    const float4v* __restrict__ in, ushort4v* __restrict__ out, int n4) {
  int i = blockIdx.x * blockDim.x + threadIdx.x;
  int stride = gridDim.x * blockDim.x;
  for (; i < n4; i += stride) {
    float4v v = in[i];
    ushort4v u;
    u.x = f2bf(v.x); u.y = f2bf(v.y); u.z = f2bf(v.z); u.w = f2bf(v.w);
    out[i] = u;
  }
}

__global__ void __launch_bounds__(384, 2) gru_persistent(
    const float* __restrict__ mask,
    const float* __restrict__ w_ih_lr, const float* __restrict__ w_hh_lr,
    const float* __restrict__ b_ih_lr, const float* __restrict__ b_hh_lr,
    const float* __restrict__ w_ih_rl, const float* __restrict__ w_hh_rl,
    const float* __restrict__ b_ih_rl, const float* __restrict__ b_hh_rl,
    const unsigned short* __restrict__ xbf,   // feats cast to bf16 [B][L][IN]
    unsigned short* __restrict__ hex,         // h exchange [dir][bg][parity][16][H] bf16
    unsigned int* __restrict__ cnt,           // arrival counters [dir][bg][L]
    float* __restrict__ out)                  // [B][L][2H]
{
  const int bx  = blockIdx.x;
  const int dir = bx >> 7;
  const int bg  = (bx >> 5) & 3;
  const int col = bx & 31;
  const int j0  = col << 4;
  const int grp = (dir << 2) | bg;

  const float* w_ih = dir ? w_ih_rl : w_ih_lr;
  const float* w_hh = dir ? w_hh_rl : w_hh_lr;
  const float* b_ih = dir ? b_ih_rl : b_ih_lr;
  const float* b_hh = dir ? b_hh_rl : b_hh_lr;

  const int tid  = threadIdx.x;
  const int wv   = tid >> 6;
  const int lane = tid & 63;
  const int n16  = lane & 15;
  const int quad = lane >> 4;
  const bool isGH = (wv < 3);
  const int nt   = isGH ? wv : (wv - 3);   // 0=r, 1=z, 2=n gate strip

  __shared__ float cg[2][3][16][16];       // [gh/gx][gate][row=batch][col=j]

  // ---- stationary weight fragments: B[k][n] = W[nt*H + j0 + n][k], bf16 ----
  const float* Wsrc = isGH ? w_hh : w_ih;
  const int grow = nt * H_ + j0 + n16;
  short8 bfrag[16];
#pragma unroll
  for (int ks = 0; ks < 16; ++ks) {
    const float* p = Wsrc + (size_t)grow * IN_ + ks * 32 + quad * 8;
    short8 f;
#pragma unroll
    for (int j = 0; j < 8; ++j) f[j] = (short)f2bf(p[j]);
    bfrag[ks] = f;
  }

  // ---- wave0 epilogue constants + fp32 hidden-state slice ----
  float b_r = 0.f, b_z = 0.f, b_nx = 0.f, b_nh = 0.f;
  float hprev[4] = {0.f, 0.f, 0.f, 0.f};
  if (wv == 0) {
    const int j = j0 + n16;
    b_r  = b_ih[j] + b_hh[j];
    b_z  = b_ih[H_ + j] + b_hh[H_ + j];
    b_nx = b_ih[2 * H_ + j];
    b_nh = b_hh[2 * H_ + j];
  }

  for (int t = 0; t < L_; ++t) {
    const int tx = dir ? (L_ - 1 - t) : t;
    float4v acc0 = {0.f, 0.f, 0.f, 0.f};
    float4v acc1 = acc0, acc2 = acc0, acc3 = acc0;

    if (isGH) {
      if (t > 0) {
        const unsigned cidx = (unsigned)(grp * L_ + (t - 1));
        if (lane == 0) {
          while (__hip_atomic_load(&cnt[cidx], __ATOMIC_RELAXED,
                                   __HIP_MEMORY_SCOPE_AGENT) < 32u)
            __builtin_amdgcn_s_sleep(2);
        }
        __threadfence();  // acquire: make remote h slices visible
        const unsigned short* hb =
            hex + (((grp << 1) | ((t - 1) & 1)) * (16 * H_)) + n16 * H_ + quad * 8;
        short8 af[16];
#pragma unroll
        for (int ks = 0; ks < 16; ++ks) af[ks] = *(const short8*)(hb + ks * 32);
#pragma unroll
        for (int ks = 0; ks < 16; ks += 4) {
          acc0 = __builtin_amdgcn_mfma_f32_16x16x32_bf16(af[ks + 0], bfrag[ks + 0], acc0, 0, 0, 0);
          acc1 = __builtin_amdgcn_mfma_f32_16x16x32_bf16(af[ks + 1], bfrag[ks + 1], acc1, 0, 0, 0);
          acc2 = __builtin_amdgcn_mfma_f32_16x16x32_bf16(af[ks + 2], bfrag[ks + 2], acc2, 0, 0, 0);
          acc3 = __builtin_amdgcn_mfma_f32_16x16x32_bf16(af[ks + 3], bfrag[ks + 3], acc3, 0, 0, 0);
        }
      }
    } else {
      const unsigned short* xb =
          xbf + ((size_t)((bg * 16 + n16) * L_ + tx)) * IN_ + quad * 8;
      short8 af[16];
#pragma unroll
      for (int ks = 0; ks < 16; ++ks) af[ks] = *(const short8*)(xb + ks * 32);
#pragma unroll
      for (int ks = 0; ks < 16; ks += 4) {
        acc0 = __builtin_amdgcn_mfma_f32_16x16x32_bf16(af[ks + 0], bfrag[ks + 0], acc0, 0, 0, 0);
        acc1 = __builtin_amdgcn_mfma_f32_16x16x32_bf16(af[ks + 1], bfrag[ks + 1], acc1, 0, 0, 0);
        acc2 = __builtin_amdgcn_mfma_f32_16x16x32_bf16(af[ks + 2], bfrag[ks + 2], acc2, 0, 0, 0);
        acc3 = __builtin_amdgcn_mfma_f32_16x16x32_bf16(af[ks + 3], bfrag[ks + 3], acc3, 0, 0, 0);
      }
    }
    float4v acc = (acc0 + acc1) + (acc2 + acc3);

    {  // C/D layout: D[row=quad*4+i][col=n16]
      float* dst = &cg[isGH ? 0 : 1][nt][0][0];
#pragma unroll
      for (int i = 0; i < 4; ++i) dst[(quad * 4 + i) * 16 + n16] = acc[i];
    }
    __syncthreads();

    if (wv == 0) {
      const int c = n16;
      const int j = j0 + c;
      unsigned short* hw = hex + (((grp << 1) | (t & 1)) * (16 * H_));
#pragma unroll
      for (int i = 0; i < 4; ++i) {
        const int row = quad * 4 + i;
        const float hr = cg[0][0][row][c], hz = cg[0][1][row][c], hn = cg[0][2][row][c];
        const float xr = cg[1][0][row][c], xz = cg[1][1][row][c], xn = cg[1][2][row][c];
        const float r = 1.f / (1.f + __expf(-(xr + hr + b_r)));
        const float z = 1.f / (1.f + __expf(-(xz + hz + b_z)));
        const float nn = tanhf(xn + b_nx + r * (hn + b_nh));
        const float hp = hprev[i];
        const float hnew = (1.f - z) * nn + z * hp;
        const int brow = bg * 16 + row;
        const float mk = mask[brow * L_ + tx];
        const float h = mk * hnew + (1.f - mk) * hp;
        hprev[i] = h;
        hw[row * H_ + j] = f2bf(h);
        out[((size_t)brow * L_ + tx) * (2 * H_) + dir * H_ + j] = h;
      }
      __threadfence();  // release h slice before signaling
      if (lane == 0) {
        __hip_atomic_fetch_add(&cnt[grp * L_ + t], 1u, __ATOMIC_RELEASE,
                               __HIP_MEMORY_SCOPE_AGENT);
      }
    }
    __syncthreads();
  }
}

extern "C" void kernel_launch(void* const* d_in, const int* in_sizes, int n_in,
                              void* d_out, int out_size, void* d_ws, size_t ws_size,
                              hipStream_t stream) {
  (void)in_sizes; (void)n_in; (void)out_size; (void)ws_size;
  const float* feats   = (const float*)d_in[0];
  const float* mask    = (const float*)d_in[1];
  const float* w_ih_lr = (const float*)d_in[2];
  const float* w_hh_lr = (const float*)d_in[3];
  const float* b_ih_lr = (const float*)d_in[4];
  const float* b_hh_lr = (const float*)d_in[5];
  const float* w_ih_rl = (const float*)d_in[6];
  const float* w_hh_rl = (const float*)d_in[7];
  const float* b_ih_rl = (const float*)d_in[8];
  const float* b_hh_rl = (const float*)d_in[9];
  float* out = (float*)d_out;

  // workspace layout
  unsigned short* xbf = (unsigned short*)d_ws;            // 64*1024*512 bf16 = 64 MiB
  unsigned short* hex = xbf + (size_t)B_ * L_ * IN_;      // 16 bufs * 16*512 bf16 = 256 KiB
  unsigned int*   cnt = (unsigned int*)(hex + 16 * 16 * H_); // 8*1024 u32 = 32 KiB

  hipMemsetAsync(cnt, 0, 8 * L_ * sizeof(unsigned int), stream);

  const int n4 = (B_ * L_ * IN_) / 4;
  cast_bf16_kernel<<<1024, 512, 0, stream>>>((const float4v*)feats, (ushort4v*)xbf, n4);

  gru_persistent<<<256, 384, 0, stream>>>(
      mask, w_ih_lr, w_hh_lr, b_ih_lr, b_hh_lr,
      w_ih_rl, w_hh_rl, b_ih_rl, b_hh_rl,
      xbf, hex, cnt, out);
}

// Round 2
// 6869.384 us; speedup vs baseline: 4.4151x; 4.4151x over previous
//
#include <hip/hip_runtime.h>
#include <hip/hip_bf16.h>

// Bidirectional masked GRU: B=64, L=1024, IN=512, H=512, fp32 in/out.
// Persistent kernel: 256 blocks (1/CU), 6 waves each.
//   block -> (dir, batch-group [16 rows], col-block [16 h-cols])
//   waves 0..2: gh = h @ w_hh^T (r,z,n); waves 3..5: gx = x @ w_ih^T (r,z,n).
//   w fragments register-resident. h exchanged per step via L3-coherent
//   RELAXED AGENT-scope atomics (sc1, bypass L1/L2) -- NO fences (no wbl2/inv
//   L2 tag-walks, which were ~30us/step in round 1). Release ordering:
//   data stores -> s_waitcnt(0) -> flag store. Acquire: in-order wave issue
//   after poll branch + compiler signal fence.

#define B_  64
#define L_  1024
#define IN_ 512
#define H_  512

using float4v  = __attribute__((ext_vector_type(4))) float;
using short8   = __attribute__((ext_vector_type(8))) short;
using ushort4v = __attribute__((ext_vector_type(4))) unsigned short;

__device__ __forceinline__ unsigned short f2bf(float f) {
  // round-to-nearest-even bf16 (finite inputs)
  unsigned u = __float_as_uint(f);
  unsigned r = (u + 0x7fffu + ((u >> 16) & 1u)) >> 16;
  return (unsigned short)r;
}

__global__ void __launch_bounds__(512) cast_bf16_kernel(
    const float4v* __restrict__ in, ushort4v* __restrict__ out, int n4) {
  int i = blockIdx.x * blockDim.x + threadIdx.x;
  int stride = gridDim.x * blockDim.x;
  for (; i < n4; i += stride) {
    float4v v = in[i];
    ushort4v u;
    u.x = f2bf(v.x); u.y = f2bf(v.y); u.z = f2bf(v.z); u.w = f2bf(v.w);
    out[i] = u;
  }
}

__device__ __forceinline__ short8 load_h16(const unsigned long long* p) {
  union { unsigned long long u[2]; short8 s; } v;
  v.u[0] = __hip_atomic_load(p,     __ATOMIC_RELAXED, __HIP_MEMORY_SCOPE_AGENT);
  v.u[1] = __hip_atomic_load(p + 1, __ATOMIC_RELAXED, __HIP_MEMORY_SCOPE_AGENT);
  return v.s;
}

__global__ void __launch_bounds__(384, 2) gru_persistent(
    const float* __restrict__ mask,
    const float* __restrict__ w_ih_lr, const float* __restrict__ w_hh_lr,
    const float* __restrict__ b_ih_lr, const float* __restrict__ b_hh_lr,
    const float* __restrict__ w_ih_rl, const float* __restrict__ w_hh_rl,
    const float* __restrict__ b_ih_rl, const float* __restrict__ b_hh_rl,
    const unsigned short* __restrict__ xbf,   // feats bf16 [B][L][IN]
    unsigned short* __restrict__ hex,         // h exchange [grp][parity][16][H] bf16
    unsigned int* __restrict__ flags,         // [grp][L][32 colblocks]
    float* __restrict__ out)                  // [B][L][2H]
{
  const int bx  = blockIdx.x;
  const int dir = bx >> 7;
  const int bg  = (bx >> 5) & 3;
  const int col = bx & 31;
  const int j0  = col << 4;
  const int grp = (dir << 2) | bg;

  const float* w_ih = dir ? w_ih_rl : w_ih_lr;
  const float* w_hh = dir ? w_hh_rl : w_hh_lr;
  const float* b_ih = dir ? b_ih_rl : b_ih_lr;
  const float* b_hh = dir ? b_hh_rl : b_hh_lr;

  const int tid  = threadIdx.x;
  const int wv   = tid >> 6;
  const int lane = tid & 63;
  const int n16  = lane & 15;
  const int quad = lane >> 4;
  const bool isGH = (wv < 3);
  const int nt   = isGH ? wv : (wv - 3);   // 0=r, 1=z, 2=n gate strip

  __shared__ float cg[2][3][16][17];       // [gh/gx][gate][row=batch][col] (+1 pad)
  __shared__ float hsh[16][17];            // wave0 h repack staging

  // ---- stationary weight fragments: B[k][n] = W[nt*H + j0 + n][k], bf16 ----
  const float* Wsrc = isGH ? w_hh : w_ih;
  const int grow = nt * H_ + j0 + n16;
  short8 bfrag[16];
#pragma unroll
  for (int ks = 0; ks < 16; ++ks) {
    const float* p = Wsrc + (size_t)grow * IN_ + ks * 32 + quad * 8;
    short8 f;
#pragma unroll
    for (int j = 0; j < 8; ++j) f[j] = (short)f2bf(p[j]);
    bfrag[ks] = f;
  }

  // ---- wave0 epilogue constants + fp32 hidden-state slice ----
  float b_r = 0.f, b_z = 0.f, b_nx = 0.f, b_nh = 0.f;
  float hprev[4] = {0.f, 0.f, 0.f, 0.f};
  if (wv == 0) {
    const int j = j0 + n16;
    b_r  = b_ih[j] + b_hh[j];
    b_z  = b_ih[H_ + j] + b_hh[H_ + j];
    b_nx = b_ih[2 * H_ + j];
    b_nh = b_hh[2 * H_ + j];
  }

  for (int t = 0; t < L_; ++t) {
    const int tx = dir ? (L_ - 1 - t) : t;

    // prefetch mask values for the epilogue (off critical path)
    float mk[4];
    if (wv == 0) {
#pragma unroll
      for (int i = 0; i < 4; ++i)
        mk[i] = mask[(bg * 16 + quad * 4 + i) * L_ + tx];
    }

    float4v acc0 = {0.f, 0.f, 0.f, 0.f};
    float4v acc1 = acc0, acc2 = acc0, acc3 = acc0;

    if (isGH) {
      if (t > 0) {
        // wait until all 32 col-blocks of this group published h(t-1)
        const unsigned int* fl = flags + (size_t)grp * (L_ * 32) + (size_t)(t - 1) * 32;
        for (;;) {
          unsigned v = __hip_atomic_load(fl + (lane & 31), __ATOMIC_RELAXED,
                                         __HIP_MEMORY_SCOPE_AGENT);
          if (__ballot(v != 0u) == ~0ull) break;
          __builtin_amdgcn_s_sleep(1);
        }
        __atomic_signal_fence(__ATOMIC_ACQUIRE);

        const unsigned long long* hb64 =
            (const unsigned long long*)(hex + (((grp << 1) | ((t - 1) & 1)) * (16 * H_)))
            + (n16 * H_ + quad * 8) / 4;
        short8 af[16];
#pragma unroll
        for (int ks = 0; ks < 16; ++ks) af[ks] = load_h16(hb64 + ks * 8);
#pragma unroll
        for (int ks = 0; ks < 16; ks += 4) {
          acc0 = __builtin_amdgcn_mfma_f32_16x16x32_bf16(af[ks + 0], bfrag[ks + 0], acc0, 0, 0, 0);
          acc1 = __builtin_amdgcn_mfma_f32_16x16x32_bf16(af[ks + 1], bfrag[ks + 1], acc1, 0, 0, 0);
          acc2 = __builtin_amdgcn_mfma_f32_16x16x32_bf16(af[ks + 2], bfrag[ks + 2], acc2, 0, 0, 0);
          acc3 = __builtin_amdgcn_mfma_f32_16x16x32_bf16(af[ks + 3], bfrag[ks + 3], acc3, 0, 0, 0);
        }
      }
    } else {
      const unsigned short* xb =
          xbf + ((size_t)((bg * 16 + n16) * L_ + tx)) * IN_ + quad * 8;
      short8 af[16];
#pragma unroll
      for (int ks = 0; ks < 16; ++ks) af[ks] = *(const short8*)(xb + ks * 32);
#pragma unroll
      for (int ks = 0; ks < 16; ks += 4) {
        acc0 = __builtin_amdgcn_mfma_f32_16x16x32_bf16(af[ks + 0], bfrag[ks + 0], acc0, 0, 0, 0);
        acc1 = __builtin_amdgcn_mfma_f32_16x16x32_bf16(af[ks + 1], bfrag[ks + 1], acc1, 0, 0, 0);
        acc2 = __builtin_amdgcn_mfma_f32_16x16x32_bf16(af[ks + 2], bfrag[ks + 2], acc2, 0, 0, 0);
        acc3 = __builtin_amdgcn_mfma_f32_16x16x32_bf16(af[ks + 3], bfrag[ks + 3], acc3, 0, 0, 0);
      }
    }
    float4v acc = (acc0 + acc1) + (acc2 + acc3);

    {  // C/D layout: D[row=quad*4+i][col=n16]
      float* dst = &cg[isGH ? 0 : 1][nt][0][0];
#pragma unroll
      for (int i = 0; i < 4; ++i) dst[(quad * 4 + i) * 17 + n16] = acc[i];
    }
    __syncthreads();

    if (wv == 0) {
      const int c = n16;
      // ---- compute h slice (fp32 state) ----
#pragma unroll
      for (int i = 0; i < 4; ++i) {
        const int row = quad * 4 + i;
        const float hr = cg[0][0][row][c], hz = cg[0][1][row][c], hn = cg[0][2][row][c];
        const float xr = cg[1][0][row][c], xz = cg[1][1][row][c], xn = cg[1][2][row][c];
        const float r = 1.f / (1.f + __expf(-(xr + hr + b_r)));
        const float z = 1.f / (1.f + __expf(-(xz + hz + b_z)));
        const float nn = tanhf(xn + b_nx + r * (hn + b_nh));
        const float hp = hprev[i];
        const float hnew = (1.f - z) * nn + z * hp;
        const float h = mk[i] * hnew + (1.f - mk[i]) * hp;
        hprev[i] = h;
        hsh[row][c] = h;
      }
      // ---- publish h (packed bf16 pairs) via L3-coherent stores ----
      unsigned* hw32 = (unsigned*)(hex + (((grp << 1) | (t & 1)) * (16 * H_)));
#pragma unroll
      for (int d = lane; d < 128; d += 64) {
        const int row = d >> 3, c8 = d & 7;
        const unsigned p = (unsigned)f2bf(hsh[row][2 * c8]) |
                           ((unsigned)f2bf(hsh[row][2 * c8 + 1]) << 16);
        __hip_atomic_store(&hw32[row * (H_ / 2) + (j0 >> 1) + c8], p,
                           __ATOMIC_RELAXED, __HIP_MEMORY_SCOPE_AGENT);
      }
      __atomic_signal_fence(__ATOMIC_RELEASE);
      __builtin_amdgcn_s_waitcnt(0);  // data stores acked at coherence point
      if (lane == 0) {
        __hip_atomic_store(&flags[(size_t)grp * (L_ * 32) + (size_t)t * 32 + col],
                           1u, __ATOMIC_RELAXED, __HIP_MEMORY_SCOPE_AGENT);
      }
      // ---- out stores off the critical path ----
#pragma unroll
      for (int i = 0; i < 4; ++i) {
        const int brow = bg * 16 + quad * 4 + i;
        out[((size_t)brow * L_ + tx) * (2 * H_) + dir * H_ + j0 + c] = hprev[i];
      }
    }
    __syncthreads();
  }
}

extern "C" void kernel_launch(void* const* d_in, const int* in_sizes, int n_in,
                              void* d_out, int out_size, void* d_ws, size_t ws_size,
                              hipStream_t stream) {
  (void)in_sizes; (void)n_in; (void)out_size; (void)ws_size;
  const float* feats   = (const float*)d_in[0];
  const float* mask    = (const float*)d_in[1];
  const float* w_ih_lr = (const float*)d_in[2];
  const float* w_hh_lr = (const float*)d_in[3];
  const float* b_ih_lr = (const float*)d_in[4];
  const float* b_hh_lr = (const float*)d_in[5];
  const float* w_ih_rl = (const float*)d_in[6];
  const float* w_hh_rl = (const float*)d_in[7];
  const float* b_ih_rl = (const float*)d_in[8];
  const float* b_hh_rl = (const float*)d_in[9];
  float* out = (float*)d_out;

  // workspace layout
  unsigned short* xbf = (unsigned short*)d_ws;              // 64 MiB
  unsigned short* hex = xbf + (size_t)B_ * L_ * IN_;        // 8*2*16*512*2B = 256 KiB
  unsigned int* flags = (unsigned int*)(hex + 16 * 16 * H_); // 8*1024*32*4B = 1 MiB

  hipMemsetAsync(flags, 0, (size_t)8 * L_ * 32 * sizeof(unsigned int), stream);

  const int n4 = (B_ * L_ * IN_) / 4;
  cast_bf16_kernel<<<1024, 512, 0, stream>>>((const float4v*)feats, (ushort4v*)xbf, n4);

  gru_persistent<<<256, 384, 0, stream>>>(
      mask, w_ih_lr, w_hh_lr, b_ih_lr, b_hh_lr,
      w_ih_rl, w_hh_rl, b_ih_rl, b_hh_rl,
      xbf, hex, flags, out);
}